// Round 1
// baseline (1290.449 us; speedup 1.0000x reference)
//
#include <hip/hip_runtime.h>
#include <hip/hip_bf16.h>
#include <math.h>

#define B_N   1024
#define M_N   200000
#define DIN   256
#define DIMN  128
#define DOUT  10
#define EPS_F 1e-7f
#define M_PAD 200064   // 1563 * 128

typedef __bf16 bf16_t;
typedef __bf16 bf16x8 __attribute__((ext_vector_type(8)));
typedef float  f32x4  __attribute__((ext_vector_type(4)));

// ---------- small utility kernels ----------

__global__ void cvt_w_kernel(const float* __restrict__ W, bf16_t* __restrict__ Wb){
    int i = blockIdx.x*256 + threadIdx.x;
    if (i < DIMN*DIN) Wb[i] = (bf16_t)W[i];
}

__global__ void hist_kernel(const int* __restrict__ cy, int* __restrict__ hist){
    __shared__ int h[DOUT];
    if (threadIdx.x < DOUT) h[threadIdx.x] = 0;
    __syncthreads();
    for (int i = blockIdx.x*blockDim.x + threadIdx.x; i < M_N; i += gridDim.x*blockDim.x)
        atomicAdd(&h[cy[i]], 1);
    __syncthreads();
    if (threadIdx.x < DOUT) atomicAdd(&hist[threadIdx.x], h[threadIdx.x]);
}

__global__ void prefix_kernel(const int* __restrict__ hist, int* __restrict__ cs){
    if (threadIdx.x == 0 && blockIdx.x == 0){
        int acc = 0;
        for (int c = 0; c < DOUT; ++c){ cs[c] = acc; acc += hist[c]; }
        cs[DOUT] = acc;   // == M_N
    }
}

// ---------- encoder: out[pos[m]] = bf16(src[m] @ Wb^T), onorm[pos[m]] = ||row||^2 ----------
// 128 rows x 128 dims per block, 4 waves in 2x2, 64x64 per wave, K=256 (8 MFMA k-steps).

__global__ __launch_bounds__(256) void encode_kernel(
    const float* __restrict__ src, const bf16_t* __restrict__ Wb,
    bf16_t* __restrict__ out, float* __restrict__ onorm, int N,
    const int* __restrict__ ycls, int* __restrict__ counters,
    const int* __restrict__ cs)
{
    __shared__ int   posL[128];
    __shared__ float nbuf[128][2];
    const int tid = threadIdx.x;
    const int r0  = blockIdx.x*128;

    if (tid < 128){
        int rs = r0 + tid;
        int p  = rs;
        if (ycls != nullptr && rs < N){
            int c = ycls[rs];
            p = cs[c] + atomicAdd(&counters[c], 1);   // class-bucketed scatter position
        }
        posL[tid] = p;
    }
    __syncthreads();

    const int lane = tid & 63, wid = tid >> 6;
    const int wr = wid >> 1, wc = wid & 1;
    const int l15 = lane & 15, quad = lane >> 4;
    const int rbase = r0 + wr*64;
    const int cbase = wc*64;

    f32x4 acc[4][4] = {};
    #pragma unroll
    for (int ks = 0; ks < 8; ++ks){
        const int k = ks*32 + quad*8;
        bf16x8 a[4], b[4];
        #pragma unroll
        for (int rt = 0; rt < 4; ++rt){
            int rr = rbase + rt*16 + l15; if (rr > N-1) rr = N-1;
            const float4* p4 = (const float4*)(src + (size_t)rr*DIN + k);
            float4 f0 = p4[0], f1 = p4[1];
            bf16x8 v;
            v[0]=(bf16_t)f0.x; v[1]=(bf16_t)f0.y; v[2]=(bf16_t)f0.z; v[3]=(bf16_t)f0.w;
            v[4]=(bf16_t)f1.x; v[5]=(bf16_t)f1.y; v[6]=(bf16_t)f1.z; v[7]=(bf16_t)f1.w;
            a[rt] = v;
        }
        #pragma unroll
        for (int ct = 0; ct < 4; ++ct){
            int cc = cbase + ct*16 + l15;
            b[ct] = *(const bf16x8*)(Wb + (size_t)cc*DIN + k);
        }
        #pragma unroll
        for (int rt = 0; rt < 4; ++rt)
            #pragma unroll
            for (int ct = 0; ct < 4; ++ct)
                acc[rt][ct] = __builtin_amdgcn_mfma_f32_16x16x32_bf16(a[rt], b[ct], acc[rt][ct], 0, 0, 0);
    }

    // per-lane partial ||row||^2 over this lane's 4 columns, then butterfly over the 16-lane col group
    float np[4][4];
    #pragma unroll
    for (int rt = 0; rt < 4; ++rt)
        #pragma unroll
        for (int r = 0; r < 4; ++r){
            float s = 0.f;
            #pragma unroll
            for (int ct = 0; ct < 4; ++ct){ float v = acc[rt][ct][r]; s += v*v; }
            np[rt][r] = s;
        }
    #pragma unroll
    for (int m = 1; m < 16; m <<= 1)
        #pragma unroll
        for (int rt = 0; rt < 4; ++rt)
            #pragma unroll
            for (int r = 0; r < 4; ++r)
                np[rt][r] += __shfl_xor(np[rt][r], m, 64);
    if (l15 == 0){
        #pragma unroll
        for (int rt = 0; rt < 4; ++rt)
            #pragma unroll
            for (int r = 0; r < 4; ++r)
                nbuf[wr*64 + rt*16 + quad*4 + r][wc] = np[rt][r];
    }

    // scatter-store bf16 rows (C/D layout: col = l15, row = quad*4 + r)
    #pragma unroll
    for (int rt = 0; rt < 4; ++rt){
        #pragma unroll
        for (int r = 0; r < 4; ++r){
            int rl = wr*64 + rt*16 + quad*4 + r;
            if (r0 + rl < N){
                size_t rowp = (size_t)posL[rl]*DIMN;
                #pragma unroll
                for (int ct = 0; ct < 4; ++ct)
                    out[rowp + cbase + ct*16 + l15] = (bf16_t)acc[rt][ct][r];
            }
        }
    }
    __syncthreads();
    if (tid < 128){
        int rs = r0 + tid;
        if (rs < N) onorm[posL[tid]] = nbuf[tid][0] + nbuf[tid][1];
    }
}

// ---------- fused dist -> exp -> class-segmented row sums ----------
// Grid (8 row-blocks, 1563 col-blocks). 128x128 tile / block, 64x64 per wave, K=128.
// Candidates are sorted by class, so a col-block spans 1 class (rarely 2+).

__device__ __forceinline__ void bfly16(float (&s)[4][4]){
    #pragma unroll
    for (int m = 1; m < 16; m <<= 1)
        #pragma unroll
        for (int rt = 0; rt < 4; ++rt)
            #pragma unroll
            for (int r = 0; r < 4; ++r)
                s[rt][r] += __shfl_xor(s[rt][r], m, 64);
}

__global__ __launch_bounds__(256) void fused_kernel(
    const bf16_t* __restrict__ hb, const bf16_t* __restrict__ hcb,
    const float* __restrict__ hn, const float* __restrict__ hcn,
    const int* __restrict__ csg, float* __restrict__ accG)
{
    const int tid = threadIdx.x;
    const int lane = tid & 63, wid = tid >> 6;
    const int wr = wid >> 1, wc = wid & 1;
    const int l15 = lane & 15, quad = lane >> 4;
    const int rbase  = blockIdx.x*128 + wr*64;
    const int cbase0 = blockIdx.y*128;
    const int cbase  = cbase0 + wc*64;

    f32x4 acc[4][4] = {};
    #pragma unroll
    for (int ks = 0; ks < 4; ++ks){
        const int k = ks*32 + quad*8;
        bf16x8 a[4], b[4];
        #pragma unroll
        for (int rt = 0; rt < 4; ++rt)
            a[rt] = *(const bf16x8*)(hb + (size_t)(rbase + rt*16 + l15)*DIMN + k);
        #pragma unroll
        for (int ct = 0; ct < 4; ++ct){
            int cc = cbase + ct*16 + l15; if (cc > M_N-1) cc = M_N-1;
            b[ct] = *(const bf16x8*)(hcb + (size_t)cc*DIMN + k);
        }
        #pragma unroll
        for (int rt = 0; rt < 4; ++rt)
            #pragma unroll
            for (int ct = 0; ct < 4; ++ct)
                acc[rt][ct] = __builtin_amdgcn_mfma_f32_16x16x32_bf16(a[rt], b[ct], acc[rt][ct], 0, 0, 0);
    }

    // epilogue: e = exp(-sqrt(max(|h|^2 + |hc|^2 - 2*dot, 0)))
    float hcnv[4];
    #pragma unroll
    for (int ct = 0; ct < 4; ++ct){
        int cc = cbase + ct*16 + l15;
        hcnv[ct] = (cc < M_N) ? hcn[cc] : 1e30f;   // pad cols: dist huge -> exp == 0
    }
    float hnv[4][4];
    #pragma unroll
    for (int rt = 0; rt < 4; ++rt)
        #pragma unroll
        for (int r = 0; r < 4; ++r)
            hnv[rt][r] = hn[rbase + rt*16 + quad*4 + r];
    #pragma unroll
    for (int rt = 0; rt < 4; ++rt)
        #pragma unroll
        for (int ct = 0; ct < 4; ++ct)
            #pragma unroll
            for (int r = 0; r < 4; ++r){
                float sq = fmaxf(hnv[rt][r] + hcnv[ct] - 2.0f*acc[rt][ct][r], 0.0f);
                acc[rt][ct][r] = __expf(-sqrtf(sq));
            }

    // class segments covering this col-block (usually exactly one)
    int cs[DOUT+1];
    #pragma unroll
    for (int i = 0; i <= DOUT; ++i) cs[i] = csg[i];
    const int lastc = min(cbase0 + 127, M_N - 1);
    int cLo = 0, cHi = 0;
    #pragma unroll
    for (int c = 1; c < DOUT; ++c){
        if (cbase0 >= cs[c]) cLo = c;
        if (lastc  >= cs[c]) cHi = c;
    }

    for (int c = cLo; c <= cHi; ++c){
        const int s0 = cs[c], s1 = cs[c+1];
        float s[4][4];
        #pragma unroll
        for (int rt = 0; rt < 4; ++rt)
            #pragma unroll
            for (int r = 0; r < 4; ++r){
                float v = 0.f;
                #pragma unroll
                for (int ct = 0; ct < 4; ++ct){
                    int cc = cbase + ct*16 + l15;
                    v += (cc >= s0 && cc < s1) ? acc[rt][ct][r] : 0.f;
                }
                s[rt][r] = v;
            }
        bfly16(s);
        if (l15 == 0){
            #pragma unroll
            for (int rt = 0; rt < 4; ++rt)
                #pragma unroll
                for (int r = 0; r < 4; ++r)
                    atomicAdd(&accG[(size_t)(rbase + rt*16 + quad*4 + r)*16 + c], s[rt][r]);
        }
    }
}

__global__ void finalize_kernel(const float* __restrict__ accG, float* __restrict__ out){
    int b = blockIdx.x*blockDim.x + threadIdx.x;
    if (b < B_N){
        float v[DOUT]; float den = 0.f;
        #pragma unroll
        for (int c = 0; c < DOUT; ++c){ v[c] = accG[b*16 + c]; den += v[c]; }
        float inv = (den > 0.f) ? 1.0f/den : 0.f;
        #pragma unroll
        for (int c = 0; c < DOUT; ++c) out[b*DOUT + c] = logf(v[c]*inv + EPS_F);
    }
}

// ---------- launch ----------

extern "C" void kernel_launch(void* const* d_in, const int* in_sizes, int n_in,
                              void* d_out, int out_size, void* d_ws, size_t ws_size,
                              hipStream_t stream)
{
    const float* x  = (const float*)d_in[0];
    // d_in[1] = y (unused on eval path)
    const float* cx = (const float*)d_in[2];
    const int*   cy = (const int*)d_in[3];
    const float* W  = (const float*)d_in[4];
    // d_in[5] = b_enc: cancels exactly in ||h - hc||, skipped
    // d_in[6] = is_train (eval path)
    float* out = (float*)d_out;

    char* w = (char*)d_ws;
    size_t off = 0;
    bf16_t* hcb = (bf16_t*)(w + off); off += (size_t)M_PAD*DIMN*2;  // 51,216,384
    bf16_t* hb  = (bf16_t*)(w + off); off += (size_t)B_N*DIMN*2;    //    262,144
    float*  hcn = (float*) (w + off); off += (size_t)M_PAD*4;       //    800,256
    float*  hn  = (float*) (w + off); off += (size_t)B_N*4;         //      4,096
    bf16_t* Wb  = (bf16_t*)(w + off); off += (size_t)DIMN*DIN*2;    //     65,536
    size_t zoff = off;
    float* accG = (float*)(w + off); off += (size_t)B_N*16*4;       //     65,536
    int* hist     = (int*)(w + off); off += 64;
    int* counters = (int*)(w + off); off += 64;
    int* csg      = (int*)(w + off); off += 64;
    size_t zsize = off - zoff;

    hipMemsetAsync(w + zoff, 0, zsize, stream);
    cvt_w_kernel<<<dim3((DIMN*DIN + 255)/256), dim3(256), 0, stream>>>(W, Wb);
    hist_kernel<<<dim3(256), dim3(256), 0, stream>>>(cy, hist);
    prefix_kernel<<<dim3(1), dim3(1), 0, stream>>>(hist, csg);
    encode_kernel<<<dim3(M_PAD/128), dim3(256), 0, stream>>>(cx, Wb, hcb, hcn, M_N, cy, counters, csg);
    encode_kernel<<<dim3(B_N/128), dim3(256), 0, stream>>>(x, Wb, hb, hn, B_N, nullptr, nullptr, nullptr);
    fused_kernel<<<dim3(B_N/128, M_PAD/128), dim3(256), 0, stream>>>(hb, hcb, hn, hcn, csg, accG);
    finalize_kernel<<<dim3((B_N + 255)/256), dim3(256), 0, stream>>>(accG, out);
}

// Round 2
// 1221.017 us; speedup vs baseline: 1.0569x; 1.0569x over previous
//
#include <hip/hip_runtime.h>
#include <hip/hip_bf16.h>
#include <math.h>

#define B_N   1024
#define M_N   200000
#define DIN   256
#define DIMN  128
#define DOUT  10
#define EPS_F 1e-7f
#define M_PAD 200064   // 1563 * 128

typedef __bf16 bf16_t;
typedef __bf16 bf16x8 __attribute__((ext_vector_type(8)));
typedef float  f32x4  __attribute__((ext_vector_type(4)));

// ---------- small utility kernels ----------

__global__ void cvt_w_kernel(const float* __restrict__ W, bf16_t* __restrict__ Wb){
    int i = blockIdx.x*256 + threadIdx.x;
    if (i < DIMN*DIN) Wb[i] = (bf16_t)W[i];
}

__global__ void hist_kernel(const int* __restrict__ cy, int* __restrict__ hist){
    __shared__ int h[DOUT];
    if (threadIdx.x < DOUT) h[threadIdx.x] = 0;
    __syncthreads();
    for (int i = blockIdx.x*blockDim.x + threadIdx.x; i < M_N; i += gridDim.x*blockDim.x)
        atomicAdd(&h[cy[i]], 1);
    __syncthreads();
    if (threadIdx.x < DOUT) atomicAdd(&hist[threadIdx.x], h[threadIdx.x]);
}

__global__ void prefix_kernel(const int* __restrict__ hist, int* __restrict__ cs){
    if (threadIdx.x == 0 && blockIdx.x == 0){
        int acc = 0;
        for (int c = 0; c < DOUT; ++c){ cs[c] = acc; acc += hist[c]; }
        cs[DOUT] = acc;   // == M_N
    }
}

// ---------- encoder: out[pos[m]] = bf16(src[m] @ Wb^T), onorm[pos[m]] = ||row||^2 ----------
// 128 rows x 128 dims per block, 4 waves 2x2 of 64x64. K=256 staged through LDS in
// two 128-wide halves: coalesced float4 global reads -> packed bf16 cvt -> ds_write_b128,
// A-fragments via 16B LDS reads. W (64KB, L2-hot) read directly per-lane.

__global__ __launch_bounds__(256) void encode_kernel(
    const float* __restrict__ src, const bf16_t* __restrict__ Wb,
    bf16_t* __restrict__ out, float* __restrict__ onorm, int N,
    const int* __restrict__ ycls, int* __restrict__ counters,
    const int* __restrict__ cs)
{
    __shared__ bf16_t As[128][136];   // 128 rows x (128 + 8 pad) bf16 = 34 KB
    __shared__ int   posL[128];
    __shared__ float nbuf[128][2];
    const int tid = threadIdx.x;
    const int r0  = blockIdx.x*128;

    if (tid < 128){
        int rs = r0 + tid;
        int p  = rs;
        if (ycls != nullptr && rs < N){
            int c = ycls[rs];
            p = cs[c] + atomicAdd(&counters[c], 1);   // class-bucketed scatter position
        }
        posL[tid] = p;
    }

    const int lane = tid & 63, wid = tid >> 6;
    const int wr = wid >> 1, wc = wid & 1;
    const int l15 = lane & 15, quad = lane >> 4;
    const int cbase = wc*64;

    f32x4 acc[4][4] = {};
    #pragma unroll
    for (int kh = 0; kh < 2; ++kh){
        __syncthreads();   // As reuse from previous half (and posL visibility)
        #pragma unroll
        for (int i = 0; i < 8; ++i){
            int idx = i*256 + tid;        // 0..2047 chunks of 8 floats
            int row = idx >> 4;           // 16 chunks per 128-col row
            int col = (idx & 15)*8;
            int rr  = r0 + row; if (rr > N-1) rr = N-1;
            const float4* p4 = (const float4*)(src + (size_t)rr*DIN + kh*128 + col);
            float4 f0 = p4[0], f1 = p4[1];
            bf16x8 v;
            v[0]=(bf16_t)f0.x; v[1]=(bf16_t)f0.y; v[2]=(bf16_t)f0.z; v[3]=(bf16_t)f0.w;
            v[4]=(bf16_t)f1.x; v[5]=(bf16_t)f1.y; v[6]=(bf16_t)f1.z; v[7]=(bf16_t)f1.w;
            *(bf16x8*)&As[row][col] = v;
        }
        __syncthreads();
        #pragma unroll
        for (int ks = 0; ks < 4; ++ks){
            const int k  = ks*32 + quad*8;    // within this K-half
            const int kg = kh*128 + k;        // global K for W
            bf16x8 a[4], b[4];
            #pragma unroll
            for (int rt = 0; rt < 4; ++rt)
                a[rt] = *(const bf16x8*)&As[wr*64 + rt*16 + l15][k];
            #pragma unroll
            for (int ct = 0; ct < 4; ++ct)
                b[ct] = *(const bf16x8*)(Wb + (size_t)(cbase + ct*16 + l15)*DIN + kg);
            #pragma unroll
            for (int rt = 0; rt < 4; ++rt)
                #pragma unroll
                for (int ct = 0; ct < 4; ++ct)
                    acc[rt][ct] = __builtin_amdgcn_mfma_f32_16x16x32_bf16(a[rt], b[ct], acc[rt][ct], 0, 0, 0);
        }
    }

    // per-lane partial ||row||^2 over this lane's 4 columns, butterfly over 16-lane col group
    float np[4][4];
    #pragma unroll
    for (int rt = 0; rt < 4; ++rt)
        #pragma unroll
        for (int r = 0; r < 4; ++r){
            float s = 0.f;
            #pragma unroll
            for (int ct = 0; ct < 4; ++ct){ float v = acc[rt][ct][r]; s += v*v; }
            np[rt][r] = s;
        }
    #pragma unroll
    for (int m = 1; m < 16; m <<= 1)
        #pragma unroll
        for (int rt = 0; rt < 4; ++rt)
            #pragma unroll
            for (int r = 0; r < 4; ++r)
                np[rt][r] += __shfl_xor(np[rt][r], m, 64);
    if (l15 == 0){
        #pragma unroll
        for (int rt = 0; rt < 4; ++rt)
            #pragma unroll
            for (int r = 0; r < 4; ++r)
                nbuf[wr*64 + rt*16 + quad*4 + r][wc] = np[rt][r];
    }

    // scatter-store bf16 rows (C/D layout: col = l15, row = quad*4 + r)
    #pragma unroll
    for (int rt = 0; rt < 4; ++rt){
        #pragma unroll
        for (int r = 0; r < 4; ++r){
            int rl = wr*64 + rt*16 + quad*4 + r;
            if (r0 + rl < N){
                size_t rowp = (size_t)posL[rl]*DIMN;
                #pragma unroll
                for (int ct = 0; ct < 4; ++ct)
                    out[rowp + cbase + ct*16 + l15] = (bf16_t)acc[rt][ct][r];
            }
        }
    }
    __syncthreads();
    if (tid < 128){
        int rs = r0 + tid;
        if (rs < N) onorm[posL[tid]] = nbuf[tid][0] + nbuf[tid][1];
    }
}

// ---------- fused dist -> exp -> class-segmented row sums ----------
// Grid (8 row-blocks, 1563 col-blocks). 128x128 tile / block, 64x64 per wave, K=128.
// Candidate tile staged through LDS (coalesced); hb (256KB, L2-hot) direct.
// Candidates are class-sorted, so ~99% of col-blocks are single-class (fast path).

__device__ __forceinline__ void bfly16(float (&s)[4][4]){
    #pragma unroll
    for (int m = 1; m < 16; m <<= 1)
        #pragma unroll
        for (int rt = 0; rt < 4; ++rt)
            #pragma unroll
            for (int r = 0; r < 4; ++r)
                s[rt][r] += __shfl_xor(s[rt][r], m, 64);
}

__global__ __launch_bounds__(256) void fused_kernel(
    const bf16_t* __restrict__ hb, const bf16_t* __restrict__ hcb,
    const float* __restrict__ hn, const float* __restrict__ hcn,
    const int* __restrict__ csg, float* __restrict__ accG)
{
    __shared__ bf16_t Bs[128][136];   // 128 candidates x (128 dims + 8 pad) = 34 KB
    const int tid = threadIdx.x;
    const int lane = tid & 63, wid = tid >> 6;
    const int wr = wid >> 1, wc = wid & 1;
    const int l15 = lane & 15, quad = lane >> 4;
    const int rbase  = blockIdx.x*128 + wr*64;
    const int cbase0 = blockIdx.y*128;
    const int cbase  = cbase0 + wc*64;

    // stage candidate tile: coalesced 16B reads (wave covers 4 rows x 256B contiguous)
    #pragma unroll
    for (int i = 0; i < 8; ++i){
        int idx = i*256 + tid;
        int c   = idx >> 4;
        int k   = (idx & 15)*8;
        int cc  = cbase0 + c; if (cc > M_N-1) cc = M_N-1;
        *(bf16x8*)&Bs[c][k] = *(const bf16x8*)(hcb + (size_t)cc*DIMN + k);
    }
    __syncthreads();

    f32x4 acc[4][4] = {};
    #pragma unroll
    for (int ks = 0; ks < 4; ++ks){
        const int k = ks*32 + quad*8;
        bf16x8 a[4], b[4];
        #pragma unroll
        for (int rt = 0; rt < 4; ++rt)
            a[rt] = *(const bf16x8*)(hb + (size_t)(rbase + rt*16 + l15)*DIMN + k);
        #pragma unroll
        for (int ct = 0; ct < 4; ++ct)
            b[ct] = *(const bf16x8*)&Bs[wc*64 + ct*16 + l15][k];
        #pragma unroll
        for (int rt = 0; rt < 4; ++rt)
            #pragma unroll
            for (int ct = 0; ct < 4; ++ct)
                acc[rt][ct] = __builtin_amdgcn_mfma_f32_16x16x32_bf16(a[rt], b[ct], acc[rt][ct], 0, 0, 0);
    }

    // epilogue: e = exp(-sqrt(max(|h|^2 + |hc|^2 - 2*dot, 0)))
    float hcnv[4];
    #pragma unroll
    for (int ct = 0; ct < 4; ++ct){
        int cc = cbase + ct*16 + l15;
        hcnv[ct] = (cc < M_N) ? hcn[cc] : 1e30f;   // pad cols: dist huge -> exp == 0
    }
    float hnv[4][4];
    #pragma unroll
    for (int rt = 0; rt < 4; ++rt)
        #pragma unroll
        for (int r = 0; r < 4; ++r)
            hnv[rt][r] = hn[rbase + rt*16 + quad*4 + r];
    #pragma unroll
    for (int rt = 0; rt < 4; ++rt)
        #pragma unroll
        for (int ct = 0; ct < 4; ++ct)
            #pragma unroll
            for (int r = 0; r < 4; ++r){
                float sq = fmaxf(hnv[rt][r] + hcnv[ct] - 2.0f*acc[rt][ct][r], 0.0f);
                acc[rt][ct][r] = __expf(-__builtin_amdgcn_sqrtf(sq));
            }

    // class segments covering this col-block (usually exactly one)
    int cs[DOUT+1];
    #pragma unroll
    for (int i = 0; i <= DOUT; ++i) cs[i] = csg[i];
    const int lastc = min(cbase0 + 127, M_N - 1);
    int cLo = 0, cHi = 0;
    #pragma unroll
    for (int c = 1; c < DOUT; ++c){
        if (cbase0 >= cs[c]) cLo = c;
        if (lastc  >= cs[c]) cHi = c;
    }

    if (cLo == cHi){
        // fast path: whole tile is one class (pad cols contribute exp == 0)
        float s[4][4];
        #pragma unroll
        for (int rt = 0; rt < 4; ++rt)
            #pragma unroll
            for (int r = 0; r < 4; ++r){
                float v = 0.f;
                #pragma unroll
                for (int ct = 0; ct < 4; ++ct) v += acc[rt][ct][r];
                s[rt][r] = v;
            }
        bfly16(s);
        if (l15 == 0){
            #pragma unroll
            for (int rt = 0; rt < 4; ++rt)
                #pragma unroll
                for (int r = 0; r < 4; ++r)
                    atomicAdd(&accG[(size_t)(rbase + rt*16 + quad*4 + r)*16 + cLo], s[rt][r]);
        }
    } else {
        for (int c = cLo; c <= cHi; ++c){
            const int s0 = cs[c], s1 = cs[c+1];
            float s[4][4];
            #pragma unroll
            for (int rt = 0; rt < 4; ++rt)
                #pragma unroll
                for (int r = 0; r < 4; ++r){
                    float v = 0.f;
                    #pragma unroll
                    for (int ct = 0; ct < 4; ++ct){
                        int cc = cbase + ct*16 + l15;
                        v += (cc >= s0 && cc < s1) ? acc[rt][ct][r] : 0.f;
                    }
                    s[rt][r] = v;
                }
            bfly16(s);
            if (l15 == 0){
                #pragma unroll
                for (int rt = 0; rt < 4; ++rt)
                    #pragma unroll
                    for (int r = 0; r < 4; ++r)
                        atomicAdd(&accG[(size_t)(rbase + rt*16 + quad*4 + r)*16 + c], s[rt][r]);
            }
        }
    }
}

__global__ void finalize_kernel(const float* __restrict__ accG, float* __restrict__ out){
    int b = blockIdx.x*blockDim.x + threadIdx.x;
    if (b < B_N){
        float v[DOUT]; float den = 0.f;
        #pragma unroll
        for (int c = 0; c < DOUT; ++c){ v[c] = accG[b*16 + c]; den += v[c]; }
        float inv = (den > 0.f) ? 1.0f/den : 0.f;
        #pragma unroll
        for (int c = 0; c < DOUT; ++c) out[b*DOUT + c] = logf(v[c]*inv + EPS_F);
    }
}

// ---------- launch ----------

extern "C" void kernel_launch(void* const* d_in, const int* in_sizes, int n_in,
                              void* d_out, int out_size, void* d_ws, size_t ws_size,
                              hipStream_t stream)
{
    const float* x  = (const float*)d_in[0];
    // d_in[1] = y (unused on eval path)
    const float* cx = (const float*)d_in[2];
    const int*   cy = (const int*)d_in[3];
    const float* W  = (const float*)d_in[4];
    // d_in[5] = b_enc: cancels exactly in ||h - hc||, skipped
    // d_in[6] = is_train (eval path)
    float* out = (float*)d_out;

    char* w = (char*)d_ws;
    size_t off = 0;
    bf16_t* hcb = (bf16_t*)(w + off); off += (size_t)M_PAD*DIMN*2;  // 51,216,384
    bf16_t* hb  = (bf16_t*)(w + off); off += (size_t)B_N*DIMN*2;    //    262,144
    float*  hcn = (float*) (w + off); off += (size_t)M_PAD*4;       //    800,256
    float*  hn  = (float*) (w + off); off += (size_t)B_N*4;         //      4,096
    bf16_t* Wb  = (bf16_t*)(w + off); off += (size_t)DIMN*DIN*2;    //     65,536
    size_t zoff = off;
    float* accG = (float*)(w + off); off += (size_t)B_N*16*4;       //     65,536
    int* hist     = (int*)(w + off); off += 64;
    int* counters = (int*)(w + off); off += 64;
    int* csg      = (int*)(w + off); off += 64;
    size_t zsize = off - zoff;

    hipMemsetAsync(w + zoff, 0, zsize, stream);
    cvt_w_kernel<<<dim3((DIMN*DIN + 255)/256), dim3(256), 0, stream>>>(W, Wb);
    hist_kernel<<<dim3(256), dim3(256), 0, stream>>>(cy, hist);
    prefix_kernel<<<dim3(1), dim3(1), 0, stream>>>(hist, csg);
    encode_kernel<<<dim3(M_PAD/128), dim3(256), 0, stream>>>(cx, Wb, hcb, hcn, M_N, cy, counters, csg);
    encode_kernel<<<dim3(B_N/128), dim3(256), 0, stream>>>(x, Wb, hb, hn, B_N, nullptr, nullptr, nullptr);
    fused_kernel<<<dim3(B_N/128, M_PAD/128), dim3(256), 0, stream>>>(hb, hcb, hn, hcn, csg, accG);
    finalize_kernel<<<dim3((B_N + 255)/256), dim3(256), 0, stream>>>(accG, out);
}

// Round 3
// 476.238 us; speedup vs baseline: 2.7097x; 2.5639x over previous
//
#include <hip/hip_runtime.h>
#include <hip/hip_bf16.h>
#include <math.h>

#define B_N   1024
#define M_N   200000
#define DIN   256
#define DIMN  128
#define DOUT  10
#define EPS_F 1e-7f
#define M_PAD 200064   // 1563 * 128
#define NBY   1563     // M_PAD / 128
#define CTILES 8       // col-tiles per fused block

typedef __bf16 bf16_t;
typedef __bf16 bf16x8 __attribute__((ext_vector_type(8)));
typedef float  f32x4  __attribute__((ext_vector_type(4)));

// ---------- small utility kernels ----------

__global__ void cvt_w_kernel(const float* __restrict__ W, bf16_t* __restrict__ Wb){
    int i = blockIdx.x*256 + threadIdx.x;
    if (i < DIMN*DIN) Wb[i] = (bf16_t)W[i];
}

// hist[c*16] line-padded
__global__ void hist_kernel(const int* __restrict__ cy, int* __restrict__ hist){
    __shared__ int h[DOUT];
    if (threadIdx.x < DOUT) h[threadIdx.x] = 0;
    __syncthreads();
    for (int i = blockIdx.x*blockDim.x + threadIdx.x; i < M_N; i += gridDim.x*blockDim.x)
        atomicAdd(&h[cy[i]], 1);
    __syncthreads();
    if (threadIdx.x < DOUT) atomicAdd(&hist[threadIdx.x*16], h[threadIdx.x]);
}

__global__ void prefix_kernel(const int* __restrict__ hist, int* __restrict__ cs){
    if (threadIdx.x == 0 && blockIdx.x == 0){
        int acc = 0;
        for (int c = 0; c < DOUT; ++c){ cs[c] = acc; acc += hist[c*16]; }
        cs[DOUT] = acc;   // == M_N
    }
}

// ---------- encoder: out[pos[m]] = bf16(src[m] @ Wb^T), onorm[pos[m]] = ||row||^2 ----------
// Position assignment: LDS per-class rank + ONE padded global atomic per class per block
// (10/block instead of 128/block — the per-element same-line atomics were the 710us wall).

__global__ __launch_bounds__(256) void encode_kernel(
    const float* __restrict__ src, const bf16_t* __restrict__ Wb,
    bf16_t* __restrict__ out, float* __restrict__ onorm, int N,
    const int* __restrict__ ycls, int* __restrict__ counters,
    const int* __restrict__ cs)
{
    __shared__ bf16_t As[128][136];   // 34 KB
    __shared__ int   posL[128];
    __shared__ float nbuf[128][2];
    __shared__ int   cntL[DOUT], baseL[DOUT];
    const int tid = threadIdx.x;
    const int r0  = blockIdx.x*128;

    int myc = -1, myrank = 0;
    if (ycls != nullptr){
        if (tid < DOUT) cntL[tid] = 0;
        __syncthreads();
        if (tid < 128 && r0 + tid < N){
            myc = ycls[r0 + tid];
            myrank = atomicAdd(&cntL[myc], 1);      // LDS atomic: block-local rank
        }
        __syncthreads();
        if (tid < DOUT && cntL[tid] > 0)
            baseL[tid] = atomicAdd(&counters[tid*16], cntL[tid]);  // padded lines
        __syncthreads();
    }
    if (tid < 128)
        posL[tid] = (myc >= 0) ? (cs[myc] + baseL[myc] + myrank) : (r0 + tid);

    const int lane = tid & 63, wid = tid >> 6;
    const int wr = wid >> 1, wc = wid & 1;
    const int l15 = lane & 15, quad = lane >> 4;
    const int cbase = wc*64;

    f32x4 acc[4][4] = {};
    #pragma unroll
    for (int kh = 0; kh < 2; ++kh){
        __syncthreads();
        #pragma unroll
        for (int i = 0; i < 8; ++i){
            int idx = i*256 + tid;        // 2048 chunks of 8 floats
            int row = idx >> 4;
            int col = (idx & 15)*8;
            int rr  = r0 + row; if (rr > N-1) rr = N-1;
            const float4* p4 = (const float4*)(src + (size_t)rr*DIN + kh*128 + col);
            float4 f0 = p4[0], f1 = p4[1];
            bf16x8 v;
            v[0]=(bf16_t)f0.x; v[1]=(bf16_t)f0.y; v[2]=(bf16_t)f0.z; v[3]=(bf16_t)f0.w;
            v[4]=(bf16_t)f1.x; v[5]=(bf16_t)f1.y; v[6]=(bf16_t)f1.z; v[7]=(bf16_t)f1.w;
            *(bf16x8*)&As[row][col] = v;
        }
        __syncthreads();
        #pragma unroll
        for (int ks = 0; ks < 4; ++ks){
            const int k  = ks*32 + quad*8;
            const int kg = kh*128 + k;
            bf16x8 a[4], b[4];
            #pragma unroll
            for (int rt = 0; rt < 4; ++rt)
                a[rt] = *(const bf16x8*)&As[wr*64 + rt*16 + l15][k];
            #pragma unroll
            for (int ct = 0; ct < 4; ++ct)
                b[ct] = *(const bf16x8*)(Wb + (size_t)(cbase + ct*16 + l15)*DIN + kg);
            #pragma unroll
            for (int rt = 0; rt < 4; ++rt)
                #pragma unroll
                for (int ct = 0; ct < 4; ++ct)
                    acc[rt][ct] = __builtin_amdgcn_mfma_f32_16x16x32_bf16(a[rt], b[ct], acc[rt][ct], 0, 0, 0);
        }
    }

    // ||row||^2: per-lane partial over 4 cols, butterfly over 16-lane col group
    float np[4][4];
    #pragma unroll
    for (int rt = 0; rt < 4; ++rt)
        #pragma unroll
        for (int r = 0; r < 4; ++r){
            float s = 0.f;
            #pragma unroll
            for (int ct = 0; ct < 4; ++ct){ float v = acc[rt][ct][r]; s += v*v; }
            np[rt][r] = s;
        }
    #pragma unroll
    for (int m = 1; m < 16; m <<= 1)
        #pragma unroll
        for (int rt = 0; rt < 4; ++rt)
            #pragma unroll
            for (int r = 0; r < 4; ++r)
                np[rt][r] += __shfl_xor(np[rt][r], m, 64);
    if (l15 == 0){
        #pragma unroll
        for (int rt = 0; rt < 4; ++rt)
            #pragma unroll
            for (int r = 0; r < 4; ++r)
                nbuf[wr*64 + rt*16 + quad*4 + r][wc] = np[rt][r];
    }

    // scatter-store bf16 rows (C/D layout: col = l15, row = quad*4 + r)
    #pragma unroll
    for (int rt = 0; rt < 4; ++rt){
        #pragma unroll
        for (int r = 0; r < 4; ++r){
            int rl = wr*64 + rt*16 + quad*4 + r;
            if (r0 + rl < N){
                size_t rowp = (size_t)posL[rl]*DIMN;
                #pragma unroll
                for (int ct = 0; ct < 4; ++ct)
                    out[rowp + cbase + ct*16 + l15] = (bf16_t)acc[rt][ct][r];
            }
        }
    }
    __syncthreads();
    if (tid < 128){
        int rs = r0 + tid;
        if (rs < N) onorm[posL[tid]] = nbuf[tid][0] + nbuf[tid][1];
    }
}

// ---------- fused dist -> exp -> class-segmented row sums ----------
// Grid (8, 196). Each block: 128 rows x 8 col-tiles of 128. A-frags held in
// registers across tiles; B staged via LDS. Row-sums accumulate in registers
// while the class is unchanged (candidates are class-sorted), flushed with one
// bfly16 + atomic burst per class change: ~0.4M atomics total vs 3.2M before.

__device__ __forceinline__ void bfly16(float (&s)[4][4]){
    #pragma unroll
    for (int m = 1; m < 16; m <<= 1)
        #pragma unroll
        for (int rt = 0; rt < 4; ++rt)
            #pragma unroll
            for (int r = 0; r < 4; ++r)
                s[rt][r] += __shfl_xor(s[rt][r], m, 64);
}

__device__ __forceinline__ void flushC(float (&s)[4][4], int c, int rbase,
                                       int quad, int l15, float* __restrict__ accG){
    bfly16(s);
    if (l15 == 0){
        #pragma unroll
        for (int rt = 0; rt < 4; ++rt)
            #pragma unroll
            for (int r = 0; r < 4; ++r)
                atomicAdd(&accG[(size_t)(rbase + rt*16 + quad*4 + r)*16 + c], s[rt][r]);
    }
}

__global__ __launch_bounds__(256, 2) void fused_kernel(
    const bf16_t* __restrict__ hb, const bf16_t* __restrict__ hcb,
    const float* __restrict__ hn, const float* __restrict__ hcn,
    const int* __restrict__ csg, float* __restrict__ accG)
{
    __shared__ bf16_t Bs[128][136];   // 34 KB
    const int tid = threadIdx.x;
    const int lane = tid & 63, wid = tid >> 6;
    const int wr = wid >> 1, wc = wid & 1;
    const int l15 = lane & 15, quad = lane >> 4;
    const int rbase = blockIdx.x*128 + wr*64;

    // A fragments: fixed per block, hold in registers (64 VGPRs)
    bf16x8 a[4][4];
    #pragma unroll
    for (int ks = 0; ks < 4; ++ks)
        #pragma unroll
        for (int rt = 0; rt < 4; ++rt)
            a[ks][rt] = *(const bf16x8*)(hb + (size_t)(rbase + rt*16 + l15)*DIMN + ks*32 + quad*8);

    float hnv[4][4];
    #pragma unroll
    for (int rt = 0; rt < 4; ++rt)
        #pragma unroll
        for (int r = 0; r < 4; ++r)
            hnv[rt][r] = hn[rbase + rt*16 + quad*4 + r];

    int cseg[DOUT+1];
    #pragma unroll
    for (int i = 0; i <= DOUT; ++i) cseg[i] = csg[i];

    float s[4][4] = {};
    int curC = -1;

    for (int t = 0; t < CTILES; ++t){
        const int by = blockIdx.y*CTILES + t;
        if (by >= NBY) break;
        const int cbase0 = by*128;

        __syncthreads();
        #pragma unroll
        for (int i = 0; i < 8; ++i){
            int idx = i*256 + tid;
            int c   = idx >> 4;
            int k   = (idx & 15)*8;
            int cc  = cbase0 + c; if (cc > M_N-1) cc = M_N-1;
            *(bf16x8*)&Bs[c][k] = *(const bf16x8*)(hcb + (size_t)cc*DIMN + k);
        }
        __syncthreads();

        f32x4 acc[4][4] = {};
        #pragma unroll
        for (int ks = 0; ks < 4; ++ks){
            const int k = ks*32 + quad*8;
            bf16x8 b[4];
            #pragma unroll
            for (int ct = 0; ct < 4; ++ct)
                b[ct] = *(const bf16x8*)&Bs[wc*64 + ct*16 + l15][k];
            #pragma unroll
            for (int rt = 0; rt < 4; ++rt)
                #pragma unroll
                for (int ct = 0; ct < 4; ++ct)
                    acc[rt][ct] = __builtin_amdgcn_mfma_f32_16x16x32_bf16(a[ks][rt], b[ct], acc[rt][ct], 0, 0, 0);
        }

        // epilogue: prob = exp(-sqrt(max(|h|^2 + |hc|^2 - 2 dot, 0)))
        float hcnv[4];
        #pragma unroll
        for (int ct = 0; ct < 4; ++ct){
            int cc = cbase0 + wc*64 + ct*16 + l15;
            hcnv[ct] = (cc < M_N) ? hcn[cc] : 1e30f;   // pad: exp(-1e15) == 0
        }
        #pragma unroll
        for (int rt = 0; rt < 4; ++rt)
            #pragma unroll
            for (int ct = 0; ct < 4; ++ct)
                #pragma unroll
                for (int r = 0; r < 4; ++r){
                    float sq = fmaxf(hnv[rt][r] + hcnv[ct] - 2.0f*acc[rt][ct][r], 0.0f);
                    acc[rt][ct][r] = __expf(-__builtin_amdgcn_sqrtf(sq));
                }

        // class span of this tile (block-uniform)
        const int lastc = min(cbase0 + 127, M_N - 1);
        int cLo = 0, cHi = 0;
        #pragma unroll
        for (int c = 1; c < DOUT; ++c){
            if (cbase0 >= cseg[c]) cLo = c;
            if (lastc  >= cseg[c]) cHi = c;
        }

        if (cLo == curC && cHi == curC){
            // common path: same single class as running accumulator
            #pragma unroll
            for (int rt = 0; rt < 4; ++rt)
                #pragma unroll
                for (int r = 0; r < 4; ++r){
                    float v = 0.f;
                    #pragma unroll
                    for (int ct = 0; ct < 4; ++ct) v += acc[rt][ct][r];
                    s[rt][r] += v;
                }
        } else {
            if (curC >= 0) flushC(s, curC, rbase, quad, l15, accG);
            #pragma unroll
            for (int rt = 0; rt < 4; ++rt)
                #pragma unroll
                for (int r = 0; r < 4; ++r) s[rt][r] = 0.f;
            for (int c = cLo; c <= cHi; ++c){
                const int s0 = cseg[c], s1 = cseg[c+1];
                float m[4][4];
                #pragma unroll
                for (int rt = 0; rt < 4; ++rt)
                    #pragma unroll
                    for (int r = 0; r < 4; ++r){
                        float v = 0.f;
                        #pragma unroll
                        for (int ct = 0; ct < 4; ++ct){
                            int cc = cbase0 + wc*64 + ct*16 + l15;
                            v += (cc >= s0 && cc < s1) ? acc[rt][ct][r] : 0.f;
                        }
                        m[rt][r] = v;
                    }
                if (c == cHi){
                    #pragma unroll
                    for (int rt = 0; rt < 4; ++rt)
                        #pragma unroll
                        for (int r = 0; r < 4; ++r) s[rt][r] = m[rt][r];
                    curC = cHi;
                } else {
                    flushC(m, c, rbase, quad, l15, accG);
                }
            }
        }
    }
    if (curC >= 0) flushC(s, curC, rbase, quad, l15, accG);
}

__global__ void finalize_kernel(const float* __restrict__ accG, float* __restrict__ out){
    int b = blockIdx.x*blockDim.x + threadIdx.x;
    if (b < B_N){
        float v[DOUT]; float den = 0.f;
        #pragma unroll
        for (int c = 0; c < DOUT; ++c){ v[c] = accG[b*16 + c]; den += v[c]; }
        float inv = (den > 0.f) ? 1.0f/den : 0.f;
        #pragma unroll
        for (int c = 0; c < DOUT; ++c) out[b*DOUT + c] = logf(v[c]*inv + EPS_F);
    }
}

// ---------- launch ----------

extern "C" void kernel_launch(void* const* d_in, const int* in_sizes, int n_in,
                              void* d_out, int out_size, void* d_ws, size_t ws_size,
                              hipStream_t stream)
{
    const float* x  = (const float*)d_in[0];
    // d_in[1] = y (unused on eval path)
    const float* cx = (const float*)d_in[2];
    const int*   cy = (const int*)d_in[3];
    const float* W  = (const float*)d_in[4];
    // d_in[5] = b_enc: cancels exactly in ||h - hc||, skipped
    // d_in[6] = is_train (eval path)
    float* out = (float*)d_out;

    char* w = (char*)d_ws;
    size_t off = 0;
    bf16_t* hcb = (bf16_t*)(w + off); off += (size_t)M_PAD*DIMN*2;  // 51,216,384
    bf16_t* hb  = (bf16_t*)(w + off); off += (size_t)B_N*DIMN*2;    //    262,144
    float*  hcn = (float*) (w + off); off += (size_t)M_PAD*4;       //    800,256
    float*  hn  = (float*) (w + off); off += (size_t)B_N*4;         //      4,096
    bf16_t* Wb  = (bf16_t*)(w + off); off += (size_t)DIMN*DIN*2;    //     65,536
    size_t zoff = off;
    float* accG = (float*)(w + off); off += (size_t)B_N*16*4;       //     65,536
    int* hist     = (int*)(w + off); off += 16*DOUT*4;              // line-padded
    int* counters = (int*)(w + off); off += 16*DOUT*4;              // line-padded
    int* csg      = (int*)(w + off); off += 64;
    size_t zsize = off - zoff;

    hipMemsetAsync(w + zoff, 0, zsize, stream);
    cvt_w_kernel<<<dim3((DIMN*DIN + 255)/256), dim3(256), 0, stream>>>(W, Wb);
    hist_kernel<<<dim3(256), dim3(256), 0, stream>>>(cy, hist);
    prefix_kernel<<<dim3(1), dim3(1), 0, stream>>>(hist, csg);
    encode_kernel<<<dim3(M_PAD/128), dim3(256), 0, stream>>>(cx, Wb, hcb, hcn, M_N, cy, counters, csg);
    encode_kernel<<<dim3(B_N/128), dim3(256), 0, stream>>>(x, Wb, hb, hn, B_N, nullptr, nullptr, nullptr);
    fused_kernel<<<dim3(B_N/128, (NBY + CTILES - 1)/CTILES), dim3(256), 0, stream>>>(hb, hcb, hn, hcn, csg, accG);
    finalize_kernel<<<dim3((B_N + 255)/256), dim3(256), 0, stream>>>(accG, out);
}